// Round 1
// baseline (509.197 us; speedup 1.0000x reference)
//
#include <hip/hip_runtime.h>

// Side Window Filter — bit-exact vs harness np ref (absmax 0.0 contract).
// Math contract (DO NOT REORDER): per output, each of the 8 windows is a
// sequential __builtin_fmaf chain over its taps in row-major (i,j) order,
// fp32 accumulator starting at 0, weights fp32(1/15), fp32(1/9); replicate
// boundary; 8 iterations; fp32 iterates; fp32 d/argmin(first-idx)/update;
// final clip(|x0-res|,0,255).
//
// R11: rolling vertical window. Each thread owns 4 consecutive columns and
// walks RPT=8 output rows. The 5 source rows of the window live in
// float4 q[5][5] (mod-5 slots, fully unrolled -> static register indices).
// Prime 4 rows, then each output row loads exactly 5 float4 (1.25
// loads/output vs 6.25 before) issued ~300 fmas ahead of first use
// (window row i=4), so global latency hides under i=0..3 compute.
// FMA chain / clamp / epilogue identical to the proven R10 kernel.

static constexpr int H   = 2048;
static constexpr int W   = 2048;
static constexpr int C   = 3;
static constexpr int WC  = W * C;   // 6144 floats per row
static constexpr int RPT = 8;       // output rows per thread

template<bool FINAL>
__global__ __launch_bounds__(256)
void swf_roll(const float* __restrict__ src, float* __restrict__ dst,
              const float* __restrict__ x0) {
  const int col4 = (blockIdx.x * 256 + threadIdx.x) * 4;  // 16B-aligned
  const int h0   = blockIdx.y * RPT;

  const float w15 = 1.0f / 15.0f;   // fp32(1/15)
  const float w9  = 1.0f / 9.0f;    // fp32(1/9)

  // fast iff all taps for cols col4..col4+3 lie in [col4-8, col4+12)
  const bool fastc = (col4 >= 8) && (col4 <= WC - 12);
  if (fastc) {
    const float* colbase = src + (col4 - 8);
    float4 q[5][5];   // q[slot][j]: row (h0+m-2) lives in slot m%5

    // prime: window rows m=0..3 (abs rows h0-2 .. h0+1); top clamp only
#pragma unroll
    for (int p = 0; p < 4; ++p) {
      int hy = h0 + p - 2;
      hy = hy < 0 ? 0 : hy;
      const float4* rp = (const float4*)(colbase + (size_t)hy * WC);
#pragma unroll
      for (int j = 0; j < 5; ++j) q[p][j] = rp[j];
    }

#pragma unroll
    for (int t = 0; t < RPT; ++t) {
      // load window row m=t+4 (abs row h0+t+2) into slot (t+4)%5;
      // bottom clamp only (h0+t+2 >= 2). Consumed last (i=4) below.
      {
        int hy = h0 + t + 2;
        hy = hy > H - 1 ? H - 1 : hy;
        const float4* rp = (const float4*)(colbase + (size_t)hy * WC);
#pragma unroll
        for (int j = 0; j < 5; ++j) q[(t + 4) % 5][j] = rp[j];
      }

      float acc[4][8];
#pragma unroll
      for (int k = 0; k < 4; ++k)
#pragma unroll
        for (int m = 0; m < 8; ++m) acc[k][m] = 0.0f;
      float center[4];

#pragma unroll
      for (int i = 0; i < 5; ++i) {
        const int s = (t + i) % 5;   // compile-time after unroll
        const float r[20] = {q[s][0].x,q[s][0].y,q[s][0].z,q[s][0].w,
                             q[s][1].x,q[s][1].y,q[s][1].z,q[s][1].w,
                             q[s][2].x,q[s][2].y,q[s][2].z,q[s][2].w,
                             q[s][3].x,q[s][3].y,q[s][3].z,q[s][3].w,
                             q[s][4].x,q[s][4].y,q[s][4].z,q[s][4].w};
#pragma unroll
        for (int k = 0; k < 4; ++k) {
          // tap j of output col4+k -> r[k + 3j + 2]
          const float t0 = r[k+2], t1 = r[k+5], t2 = r[k+8],
                      t3 = r[k+11], t4 = r[k+14];
          float* a = acc[k];
          if (i == 2) center[k] = t2;
          // L: cols 0..2, all rows
          a[0]=__builtin_fmaf(w15,t0,a[0]); a[0]=__builtin_fmaf(w15,t1,a[0]); a[0]=__builtin_fmaf(w15,t2,a[0]);
          // R: cols 2..4, all rows
          a[1]=__builtin_fmaf(w15,t2,a[1]); a[1]=__builtin_fmaf(w15,t3,a[1]); a[1]=__builtin_fmaf(w15,t4,a[1]);
          if (i <= 2) {  // U: rows 0..2, all cols
            a[2]=__builtin_fmaf(w15,t0,a[2]); a[2]=__builtin_fmaf(w15,t1,a[2]); a[2]=__builtin_fmaf(w15,t2,a[2]);
            a[2]=__builtin_fmaf(w15,t3,a[2]); a[2]=__builtin_fmaf(w15,t4,a[2]);
            // NW / NE
            a[4]=__builtin_fmaf(w9,t0,a[4]); a[4]=__builtin_fmaf(w9,t1,a[4]); a[4]=__builtin_fmaf(w9,t2,a[4]);
            a[5]=__builtin_fmaf(w9,t2,a[5]); a[5]=__builtin_fmaf(w9,t3,a[5]); a[5]=__builtin_fmaf(w9,t4,a[5]);
          }
          if (i >= 2) {  // D: rows 2..4, all cols
            a[3]=__builtin_fmaf(w15,t0,a[3]); a[3]=__builtin_fmaf(w15,t1,a[3]); a[3]=__builtin_fmaf(w15,t2,a[3]);
            a[3]=__builtin_fmaf(w15,t3,a[3]); a[3]=__builtin_fmaf(w15,t4,a[3]);
            // SW / SE
            a[6]=__builtin_fmaf(w9,t0,a[6]); a[6]=__builtin_fmaf(w9,t1,a[6]); a[6]=__builtin_fmaf(w9,t2,a[6]);
            a[7]=__builtin_fmaf(w9,t2,a[7]); a[7]=__builtin_fmaf(w9,t3,a[7]); a[7]=__builtin_fmaf(w9,t4,a[7]);
          }
        }
      }

      // epilogue for output row h0+t: fp32 d/argmin/update, float4 store
      const int y = h0 + t;
      float4 xv4;
      if (FINAL) xv4 = *(const float4*)(x0 + (size_t)y * WC + col4);
      float o[4];
#pragma unroll
      for (int k = 0; k < 4; ++k) {
        float best  = acc[k][0] - center[k];
        float besta = fabsf(best);
#pragma unroll
        for (int m = 1; m < 8; ++m) {
          const float d = acc[k][m] - center[k];
          const float a = fabsf(d);
          if (a < besta) { besta = a; best = d; }
        }
        const float res = center[k] + best;
        if (FINAL) {
          const float xv = (k == 0) ? xv4.x : (k == 1) ? xv4.y
                         : (k == 2) ? xv4.z : xv4.w;
          float diff = fabsf(xv - res);
          o[k] = diff > 255.0f ? 255.0f : diff;
        } else {
          o[k] = res;
        }
      }
      float4 ov;
      ov.x = o[0]; ov.y = o[1]; ov.z = o[2]; ov.w = o[3];
      *(float4*)(dst + (size_t)y * WC + col4) = ov;
    }
  } else {
    // edge columns (col4 in {0,4,WC-8,WC-4}): scalar clamped gather,
    // identical chain structure; column clamps hoisted (row-invariant)
    int cjk[4][5];
#pragma unroll
    for (int k = 0; k < 4; ++k) {
      const int col = col4 + k;
      const int w   = col / 3;
      const int c   = col - w * 3;
#pragma unroll
      for (int j = 0; j < 5; ++j) {
        int wj = w + j - 2;
        wj = wj < 0 ? 0 : (wj > W - 1 ? W - 1 : wj);   // replicate cols
        cjk[k][j] = wj * 3 + c;
      }
    }
    for (int t = 0; t < RPT; ++t) {
      const int y = h0 + t;
      float acc[4][8];
#pragma unroll
      for (int k = 0; k < 4; ++k)
#pragma unroll
        for (int m = 0; m < 8; ++m) acc[k][m] = 0.0f;
      float center[4];
#pragma unroll
      for (int k = 0; k < 4; ++k) {
        float* a = acc[k];
#pragma unroll
        for (int i = 0; i < 5; ++i) {
          int hy = y + i - 2;
          hy = hy < 0 ? 0 : (hy > H - 1 ? H - 1 : hy);
          const float* r = src + (size_t)hy * WC;
          const float t0 = r[cjk[k][0]], t1 = r[cjk[k][1]], t2 = r[cjk[k][2]],
                      t3 = r[cjk[k][3]], t4 = r[cjk[k][4]];
          if (i == 2) center[k] = t2;
          a[0]=__builtin_fmaf(w15,t0,a[0]); a[0]=__builtin_fmaf(w15,t1,a[0]); a[0]=__builtin_fmaf(w15,t2,a[0]);
          a[1]=__builtin_fmaf(w15,t2,a[1]); a[1]=__builtin_fmaf(w15,t3,a[1]); a[1]=__builtin_fmaf(w15,t4,a[1]);
          if (i <= 2) {
            a[2]=__builtin_fmaf(w15,t0,a[2]); a[2]=__builtin_fmaf(w15,t1,a[2]); a[2]=__builtin_fmaf(w15,t2,a[2]);
            a[2]=__builtin_fmaf(w15,t3,a[2]); a[2]=__builtin_fmaf(w15,t4,a[2]);
            a[4]=__builtin_fmaf(w9,t0,a[4]); a[4]=__builtin_fmaf(w9,t1,a[4]); a[4]=__builtin_fmaf(w9,t2,a[4]);
            a[5]=__builtin_fmaf(w9,t2,a[5]); a[5]=__builtin_fmaf(w9,t3,a[5]); a[5]=__builtin_fmaf(w9,t4,a[5]);
          }
          if (i >= 2) {
            a[3]=__builtin_fmaf(w15,t0,a[3]); a[3]=__builtin_fmaf(w15,t1,a[3]); a[3]=__builtin_fmaf(w15,t2,a[3]);
            a[3]=__builtin_fmaf(w15,t3,a[3]); a[3]=__builtin_fmaf(w15,t4,a[3]);
            a[6]=__builtin_fmaf(w9,t0,a[6]); a[6]=__builtin_fmaf(w9,t1,a[6]); a[6]=__builtin_fmaf(w9,t2,a[6]);
            a[7]=__builtin_fmaf(w9,t2,a[7]); a[7]=__builtin_fmaf(w9,t3,a[7]); a[7]=__builtin_fmaf(w9,t4,a[7]);
          }
        }
      }
      float o[4];
#pragma unroll
      for (int k = 0; k < 4; ++k) {
        float best  = acc[k][0] - center[k];
        float besta = fabsf(best);
#pragma unroll
        for (int m = 1; m < 8; ++m) {
          const float d = acc[k][m] - center[k];
          const float a = fabsf(d);
          if (a < besta) { besta = a; best = d; }
        }
        const float res = center[k] + best;
        if (FINAL) {
          const float xv = x0[(size_t)y * WC + col4 + k];
          float diff = fabsf(xv - res);
          o[k] = diff > 255.0f ? 255.0f : diff;
        } else {
          o[k] = res;
        }
      }
      float4 ov;
      ov.x = o[0]; ov.y = o[1]; ov.z = o[2]; ov.w = o[3];
      *(float4*)(dst + (size_t)y * WC + col4) = ov;
    }
  }
}

extern "C" void kernel_launch(void* const* d_in, const int* in_sizes, int n_in,
                              void* d_out, int out_size, void* d_ws, size_t ws_size,
                              hipStream_t stream) {
  const float* x0  = (const float*)d_in[0];
  float*       out = (float*)d_out;
  float*       ws  = (float*)d_ws;   // needs H*W*C*4 = 50.3 MB

  dim3 grid(WC / 1024, H / RPT);   // 6 x-blocks, 256 y-blocks (8 rows each)
  dim3 block(256);

  swf_roll<false><<<grid, block, 0, stream>>>(x0,  ws,  nullptr);  // iter 1
  swf_roll<false><<<grid, block, 0, stream>>>(ws,  out, nullptr);  // iter 2
  swf_roll<false><<<grid, block, 0, stream>>>(out, ws,  nullptr);  // iter 3
  swf_roll<false><<<grid, block, 0, stream>>>(ws,  out, nullptr);  // iter 4
  swf_roll<false><<<grid, block, 0, stream>>>(out, ws,  nullptr);  // iter 5
  swf_roll<false><<<grid, block, 0, stream>>>(ws,  out, nullptr);  // iter 6
  swf_roll<false><<<grid, block, 0, stream>>>(out, ws,  nullptr);  // iter 7
  swf_roll<true ><<<grid, block, 0, stream>>>(ws,  out, x0);       // iter 8 + diff
}